// Round 2
// baseline (1053.147 us; speedup 1.0000x reference)
//
#include <hip/hip_runtime.h>
#include <cstdint>
#include <cstddef>

#define HDIM  128
#define NCLS  5
#define NLEAF 65536

typedef __attribute__((ext_vector_type(8))) short short8v;   // 8 bf16 (4 VGPRs)
typedef __attribute__((ext_vector_type(4))) float f32x4;     // MFMA accumulator

__device__ __forceinline__ float sigf(float x) { return 1.0f / (1.0f + __expf(-x)); }

__device__ __forceinline__ unsigned short bf16_rne(float x) {
    unsigned u = __float_as_uint(x);
    u += 0x7FFFu + ((u >> 16) & 1u);
    return (unsigned short)(u >> 16);
}
__device__ __forceinline__ float bf16_f32(unsigned short h) {
    return __uint_as_float(((unsigned)h) << 16);
}

// Build an 8-element bf16 A-fragment from 8 consecutive f32 values.
// lo_mode (wave-uniform): 0 -> hi part, 1 -> residual lo part.
__device__ __forceinline__ short8v make_frag(const float* __restrict__ src, int lo_mode) {
    float4 f0 = *reinterpret_cast<const float4*>(src);
    float4 f1 = *reinterpret_cast<const float4*>(src + 4);
    float v[8] = { f0.x, f0.y, f0.z, f0.w, f1.x, f1.y, f1.z, f1.w };
    short8v r;
#pragma unroll
    for (int e = 0; e < 8; ++e) {
        unsigned short h = bf16_rne(v[e]);
        if (lo_mode) h = bf16_rne(v[e] - bf16_f32(h));
        r[e] = (short)h;
    }
    return r;
}

// ---------------------------------------------------------------------------
// Weight prep: level table Wt[640][512] bf16-bits.
//   cols: [Ui | Uo | Uu | Uf1(zero-padded bottom) | Uf2(zero-padded top)]
//   k-phys: [0,256) = hi(Wcat), [256,512) = lo(Wcat)
// ---------------------------------------------------------------------------
__global__ __launch_bounds__(256)
void prep_level_w(const float* __restrict__ Ui, const float* __restrict__ Uo,
                  const float* __restrict__ Uu, const float* __restrict__ Uf1,
                  const float* __restrict__ Uf2, unsigned short* __restrict__ Wt)
{
    int idx = blockIdx.x * 256 + threadIdx.x;          // 640*512
    if (idx >= 640 * 512) return;
    int col = idx >> 9;
    int kp  = idx & 511;
    int g = col >> 7, j = col & 127;
    int band = kp >> 8;
    int k = kp & 255;
    float x;
    if      (g == 0) x = Ui[k * 128 + j];
    else if (g == 1) x = Uo[k * 128 + j];
    else if (g == 2) x = Uu[k * 128 + j];
    else if (g == 3) x = (k < 128)  ? Uf1[k * 128 + j] : 0.f;
    else             x = (k >= 128) ? Uf2[(k - 128) * 128 + j] : 0.f;
    unsigned short h = bf16_rne(x);
    if (band == 1) h = bf16_rne(x - bf16_f32(h));
    Wt[(size_t)col * 512 + kp] = h;
}

// Leaf table Wt[384][256]: cols [Wi|Wo|Wu], k-phys [0,128)=hi, [128,256)=lo
__global__ __launch_bounds__(256)
void prep_leaf_w(const float* __restrict__ Wi, const float* __restrict__ Wo,
                 const float* __restrict__ Wu, unsigned short* __restrict__ Wt)
{
    int idx = blockIdx.x * 256 + threadIdx.x;          // 384*256
    if (idx >= 384 * 256) return;
    int col = idx >> 8;
    int kp  = idx & 255;
    int g = col >> 7, j = col & 127;
    int band = kp >> 7;
    int k = kp & 127;
    float x;
    if      (g == 0) x = Wi[k * 128 + j];
    else if (g == 1) x = Wo[k * 128 + j];
    else             x = Wu[k * 128 + j];
    unsigned short h = bf16_rne(x);
    if (band == 1) h = bf16_rne(x - bf16_f32(h));
    Wt[(size_t)col * 256 + kp] = h;
}

// ---------------------------------------------------------------------------
// Leaf MFMA kernel. Split GEMM: K' = 384 (Ah·Wh | Al·Wh | Ah·Wl), N = 384.
// Block 256 thr = 4 waves; BM=32 rows; wave wc handles j-blocks {wc, wc+4}.
// ---------------------------------------------------------------------------
__global__ __launch_bounds__(256)
void leaf_mfma(const int* __restrict__ words, const float* __restrict__ emb,
               const unsigned short* __restrict__ Wt,
               const float* __restrict__ bi, const float* __restrict__ bo,
               const float* __restrict__ bu,
               float* __restrict__ Hout, float* __restrict__ Cout)
{
    const int tid  = threadIdx.x;
    const int lane = tid & 63;
    const int wc   = tid >> 6;
    const int rb   = blockIdx.x * 32;
    const int l15  = lane & 15;
    const int l4   = lane >> 4;
    const int kofs = l4 * 8;

    f32x4 acc[2][2][3];
#pragma unroll
    for (int m = 0; m < 2; ++m)
#pragma unroll
        for (int jbi = 0; jbi < 2; ++jbi)
#pragma unroll
            for (int g = 0; g < 3; ++g) acc[m][jbi][g] = (f32x4){0.f, 0.f, 0.f, 0.f};

    const int r0 = rb + l15;
    const int r1 = r0 + 16;
    const int w0 = words[r0];
    const int w1 = words[r1];

    for (int ks = 0; ks < 12; ++ks) {
        int sel = (ks * 32) >> 7;               // 0:hi 1:lo 2:hi (wave-uniform)
        int k   = (ks * 32 + kofs) & 127;
        int lo_mode = (sel == 1);
        short8v A0 = make_frag(emb + (size_t)w0 * HDIM + k, lo_mode);
        short8v A1 = make_frag(emb + (size_t)w1 * HDIM + k, lo_mode);
        int bk = ((sel == 2) ? 128 : 0) + k;    // physical B k index
#pragma unroll
        for (int jbi = 0; jbi < 2; ++jbi) {
            int jb = wc + 4 * jbi;
#pragma unroll
            for (int g = 0; g < 3; ++g) {
                int col = g * 128 + jb * 16 + l15;
                short8v B = *reinterpret_cast<const short8v*>(Wt + (size_t)col * 256 + bk);
                acc[0][jbi][g] = __builtin_amdgcn_mfma_f32_16x16x32_bf16(A0, B, acc[0][jbi][g], 0, 0, 0);
                acc[1][jbi][g] = __builtin_amdgcn_mfma_f32_16x16x32_bf16(A1, B, acc[1][jbi][g], 0, 0, 0);
            }
        }
    }

#pragma unroll
    for (int m = 0; m < 2; ++m) {
#pragma unroll
        for (int jbi = 0; jbi < 2; ++jbi) {
            int j = (wc + 4 * jbi) * 16 + l15;
            float bi_ = bi[j], bo_ = bo[j], bu_ = bu[j];
#pragma unroll
            for (int v = 0; v < 4; ++v) {
                int row = rb + m * 16 + l4 * 4 + v;
                float iv = sigf(acc[m][jbi][0][v] + bi_);
                float ov = sigf(acc[m][jbi][1][v] + bo_);
                float uv = fmaxf(acc[m][jbi][2][v] + bu_, 0.f);
                float c  = iv * uv;
                float h  = ov * fmaxf(c, 0.f);
                Cout[(size_t)row * HDIM + j] = c;
                Hout[(size_t)row * HDIM + j] = h;
            }
        }
    }
}

// ---------------------------------------------------------------------------
// Level MFMA kernel. A = Hprev viewed (n x 256), split K' = 768, N = 640.
// ---------------------------------------------------------------------------
__global__ __launch_bounds__(256)
void level_mfma(const float* __restrict__ Hprev, const float* __restrict__ Cin,
                const unsigned short* __restrict__ Wt,
                const float* __restrict__ bUi, const float* __restrict__ bUo,
                const float* __restrict__ bUu, const float* __restrict__ bf1,
                const float* __restrict__ bf2,
                float* __restrict__ Hout, float* __restrict__ Cout, int n)
{
    const int tid  = threadIdx.x;
    const int lane = tid & 63;
    const int wc   = tid >> 6;
    const int rb   = blockIdx.x * 32;
    const int l15  = lane & 15;
    const int l4   = lane >> 4;
    const int kofs = l4 * 8;

    f32x4 acc[2][2][5];
#pragma unroll
    for (int m = 0; m < 2; ++m)
#pragma unroll
        for (int jbi = 0; jbi < 2; ++jbi)
#pragma unroll
            for (int g = 0; g < 5; ++g) acc[m][jbi][g] = (f32x4){0.f, 0.f, 0.f, 0.f};

    const int r0  = rb + l15;
    const int r1  = r0 + 16;
    const int ra0 = min(r0, n - 1);
    const int ra1 = min(r1, n - 1);

    for (int ks = 0; ks < 24; ++ks) {
        int sel  = (ks * 32) >> 8;              // 0:Ah·Wh 1:Al·Wh 2:Ah·Wl (uniform)
        int k    = (ks * 32 + kofs) & 255;
        int kk   = k & 127;
        int csel = k >> 7;                      // 0 -> left child, 1 -> right child
        int lo_mode = (sel == 1);
        const float* a0 = Hprev + (size_t)(2 * ra0 + csel) * HDIM + kk;
        const float* a1 = Hprev + (size_t)(2 * ra1 + csel) * HDIM + kk;
        short8v A0 = make_frag(a0, lo_mode);
        short8v A1 = make_frag(a1, lo_mode);
        int bk = ((sel == 2) ? 256 : 0) + k;    // physical B k index
#pragma unroll
        for (int jbi = 0; jbi < 2; ++jbi) {
            int jb = wc + 4 * jbi;
#pragma unroll
            for (int g = 0; g < 5; ++g) {
                int col = g * 128 + jb * 16 + l15;
                short8v B = *reinterpret_cast<const short8v*>(Wt + (size_t)col * 512 + bk);
                acc[0][jbi][g] = __builtin_amdgcn_mfma_f32_16x16x32_bf16(A0, B, acc[0][jbi][g], 0, 0, 0);
                acc[1][jbi][g] = __builtin_amdgcn_mfma_f32_16x16x32_bf16(A1, B, acc[1][jbi][g], 0, 0, 0);
            }
        }
    }

#pragma unroll
    for (int m = 0; m < 2; ++m) {
#pragma unroll
        for (int jbi = 0; jbi < 2; ++jbi) {
            int j = (wc + 4 * jbi) * 16 + l15;
            float bi_ = bUi[j], bo_ = bUo[j], bu_ = bUu[j], b1_ = bf1[j], b2_ = bf2[j];
#pragma unroll
            for (int v = 0; v < 4; ++v) {
                int row = rb + m * 16 + l4 * 4 + v;
                if (row < n) {
                    float iv  = sigf(acc[m][jbi][0][v] + bi_);
                    float ov  = sigf(acc[m][jbi][1][v] + bo_);
                    float uv  = fmaxf(acc[m][jbi][2][v] + bu_, 0.f);
                    float f1v = sigf(acc[m][jbi][3][v] + b1_);
                    float f2v = sigf(acc[m][jbi][4][v] + b2_);
                    float lC  = Cin[(size_t)(2 * row)     * HDIM + j];
                    float rC  = Cin[(size_t)(2 * row + 1) * HDIM + j];
                    float c   = fmaf(iv, uv, fmaf(f1v, lC, f2v * rC));
                    float h   = ov * fmaxf(c, 0.f);
                    Cout[(size_t)row * HDIM + j] = c;
                    Hout[(size_t)row * HDIM + j] = h;
                }
            }
        }
    }
}

// ---------------------------------------------------------------------------
// Projection: out[r] = h[r] @ P + bP    (one wave per row)
// ---------------------------------------------------------------------------
__global__ __launch_bounds__(256)
void proj_kernel(const float* __restrict__ Hbuf,
                 const float* __restrict__ P, const float* __restrict__ bP,
                 float* __restrict__ out, int total)
{
    int wid  = blockIdx.x * 4 + (threadIdx.x >> 6);
    int lane = threadIdx.x & 63;
    if (wid >= total) return;
    const float* h = Hbuf + (size_t)wid * HDIM;
    float h0 = h[lane];
    float h1 = h[lane + 64];
    float acc[NCLS];
#pragma unroll
    for (int c = 0; c < NCLS; ++c)
        acc[c] = fmaf(h0, P[lane * NCLS + c], h1 * P[(lane + 64) * NCLS + c]);
    for (int off = 32; off > 0; off >>= 1) {
#pragma unroll
        for (int c = 0; c < NCLS; ++c)
            acc[c] += __shfl_down(acc[c], off, 64);
    }
    if (lane == 0) {
#pragma unroll
        for (int c = 0; c < NCLS; ++c)
            out[(size_t)wid * NCLS + c] = acc[c] + bP[c];
    }
}

// ---------------------------------------------------------------------------
// Host launcher
// ws layout: Wt (640*512*2B = 640 KiB, leaf table overlaps, prepped serially)
//            | Hbuf f32 131072x128 | CA f32 65536x128 | CB f32 32768x128
// total ~118.1 MB
// ---------------------------------------------------------------------------
extern "C" void kernel_launch(void* const* d_in, const int* in_sizes, int n_in,
                              void* d_out, int out_size, void* d_ws, size_t ws_size,
                              hipStream_t stream)
{
    const int*   words = (const int*)  d_in[0];
    const float* emb   = (const float*)d_in[1];
    const float* Wi  = (const float*)d_in[2];  const float* bi  = (const float*)d_in[3];
    const float* Wo  = (const float*)d_in[4];  const float* bo  = (const float*)d_in[5];
    const float* Wu  = (const float*)d_in[6];  const float* bu  = (const float*)d_in[7];
    const float* Ui  = (const float*)d_in[8];  const float* bUi = (const float*)d_in[9];
    const float* Uo  = (const float*)d_in[10]; const float* bUo = (const float*)d_in[11];
    const float* Uu  = (const float*)d_in[12]; const float* bUu = (const float*)d_in[13];
    const float* Uf1 = (const float*)d_in[14]; const float* bf1 = (const float*)d_in[15];
    const float* Uf2 = (const float*)d_in[16]; const float* bf2 = (const float*)d_in[17];
    const float* P   = (const float*)d_in[18]; const float* bP  = (const float*)d_in[19];
    float* out = (float*)d_out;

    unsigned short* Wt = (unsigned short*)d_ws;                 // 640*512 elems max
    float* Hbuf = (float*)((char*)d_ws + 640 * 512 * 2);        // 131072 rows
    float* CA   = Hbuf + (size_t)131072 * HDIM;                 // 65536 rows
    float* CB   = CA   + (size_t)65536  * HDIM;                 // 32768 rows

    // 1) leaf weights -> leaf GEMM (uses Wt, then Wt is overwritten for levels)
    prep_leaf_w<<<384, 256, 0, stream>>>(Wi, Wo, Wu, Wt);
    leaf_mfma<<<NLEAF / 32, 256, 0, stream>>>(words, emb, Wt, bi, bo, bu, Hbuf, CA);

    // 2) level weights
    prep_level_w<<<1280, 256, 0, stream>>>(Ui, Uo, Uu, Uf1, Uf2, Wt);

    // 3) tree levels
    const float* cin = CA;
    float*       cot = CB;
    int n_prev = NLEAF;
    int off_prev = 0;
    int off = NLEAF;
    while (n_prev > 1) {
        int m = n_prev >> 1;
        int blocks = (m + 31) / 32;
        level_mfma<<<blocks, 256, 0, stream>>>(
            Hbuf + (size_t)off_prev * HDIM, cin, Wt,
            bUi, bUo, bUu, bf1, bf2,
            Hbuf + (size_t)off * HDIM, cot, m);
        float* tmp = (float*)cin; cin = cot; cot = tmp;
        off_prev = off;
        off += m;
        n_prev = m;
    }

    // 4) projection over all 131071 node h-vectors
    int total = off;
    proj_kernel<<<(total + 3) / 4, 256, 0, stream>>>(Hbuf, P, bP, out, total);
}

// Round 3
// 478.366 us; speedup vs baseline: 2.2016x; 2.2016x over previous
//
#include <hip/hip_runtime.h>
#include <cstdint>
#include <cstddef>

#define HDIM  128
#define NCLS  5
#define NLEAF 65536

typedef unsigned short ushort_t;
typedef __attribute__((ext_vector_type(8))) short short8v;   // 8 bf16 (4 VGPRs)
typedef __attribute__((ext_vector_type(4))) float f32x4;     // MFMA accumulator

__device__ __forceinline__ float sigf(float x) { return 1.0f / (1.0f + __expf(-x)); }

__device__ __forceinline__ unsigned short bf16_rne(float x) {
    unsigned u = __float_as_uint(x);
    u += 0x7FFFu + ((u >> 16) & 1u);
    return (unsigned short)(u >> 16);
}
__device__ __forceinline__ float bf16_f32(unsigned short h) {
    return __uint_as_float(((unsigned)h) << 16);
}

__device__ __forceinline__ void cvt_hilo(float4 f0, float4 f1, short8v& hi, short8v& lo) {
    float v[8] = { f0.x, f0.y, f0.z, f0.w, f1.x, f1.y, f1.z, f1.w };
#pragma unroll
    for (int e = 0; e < 8; ++e) {
        unsigned short h = bf16_rne(v[e]);
        unsigned short l = bf16_rne(v[e] - bf16_f32(h));
        hi[e] = (short)h; lo[e] = (short)l;
    }
}

// direct-to-LDS 16B copy: lds dest = uniform base + lane*16, global src per-lane
__device__ __forceinline__ void glds16(const ushort_t* g, ushort_t* l) {
    __builtin_amdgcn_global_load_lds((const __attribute__((address_space(1))) void*)g,
                                     (__attribute__((address_space(3))) void*)l,
                                     16, 0, 0);
}

// ---------------------------------------------------------------------------
// Weight prep into fragment order: Wt2[((chunk*NCT + ct)*64 + lane)*8 + e]
// level: NCT=40, chunks=16 (phys k 512: [0,256)=hi, [256,512)=lo)
// ---------------------------------------------------------------------------
__global__ __launch_bounds__(256)
void prep_level_w2(const float* __restrict__ Ui, const float* __restrict__ Uo,
                   const float* __restrict__ Uu, const float* __restrict__ Uf1,
                   const float* __restrict__ Uf2, ushort_t* __restrict__ Wt2)
{
    int idx = blockIdx.x * 256 + threadIdx.x;        // 16*40*64*8 = 327680
    if (idx >= 327680) return;
    int e    = idx & 7;
    int lane = (idx >> 3) & 63;
    int rest = idx >> 9;
    int ct = rest % 40;
    int chunk = rest / 40;
    int l15 = lane & 15, l4 = lane >> 4;
    int g = ct >> 3, jb = ct & 7;
    int j = jb * 16 + l15;
    int bk = chunk * 32 + l4 * 8 + e;                // [0,512)
    int band = bk >> 8;
    int k = bk & 255;
    float x;
    if      (g == 0) x = Ui[k * 128 + j];
    else if (g == 1) x = Uo[k * 128 + j];
    else if (g == 2) x = Uu[k * 128 + j];
    else if (g == 3) x = (k < 128)  ? Uf1[k * 128 + j] : 0.f;
    else             x = (k >= 128) ? Uf2[(k - 128) * 128 + j] : 0.f;
    unsigned short h = bf16_rne(x);
    if (band) h = bf16_rne(x - bf16_f32(h));
    Wt2[idx] = h;
}

// leaf: NCT=24, chunks=8 (phys k 256: [0,128)=hi, [128,256)=lo)
__global__ __launch_bounds__(256)
void prep_leaf_w2(const float* __restrict__ Wi, const float* __restrict__ Wo,
                  const float* __restrict__ Wu, ushort_t* __restrict__ Wt2)
{
    int idx = blockIdx.x * 256 + threadIdx.x;        // 8*24*64*8 = 98304
    if (idx >= 98304) return;
    int e    = idx & 7;
    int lane = (idx >> 3) & 63;
    int rest = idx >> 9;
    int ct = rest % 24;
    int chunk = rest / 24;
    int l15 = lane & 15, l4 = lane >> 4;
    int g = ct >> 3, jb = ct & 7;
    int j = jb * 16 + l15;
    int bk = chunk * 32 + l4 * 8 + e;                // [0,256)
    int band = bk >> 7;
    int k = bk & 127;
    float x;
    if      (g == 0) x = Wi[k * 128 + j];
    else if (g == 1) x = Wo[k * 128 + j];
    else             x = Wu[k * 128 + j];
    unsigned short h = bf16_rne(x);
    if (band) h = bf16_rne(x - bf16_f32(h));
    Wt2[idx] = h;
}

__device__ __forceinline__ void stage_L(const ushort_t* __restrict__ Wt2, ushort_t* buf,
                                        int c, int wc, int lane) {
#pragma unroll
    for (int s = 0; s < 10; ++s) {
        const int ct = wc * 10 + s;
        glds16(Wt2 + ((size_t)(c * 40 + ct) * 64 + lane) * 8, buf + ct * 512);
    }
}
__device__ __forceinline__ void stage_F(const ushort_t* __restrict__ Wt2, ushort_t* buf,
                                        int c, int wc, int lane) {
#pragma unroll
    for (int s = 0; s < 6; ++s) {
        const int ct = wc * 6 + s;
        glds16(Wt2 + ((size_t)(c * 24 + ct) * 64 + lane) * 8, buf + ct * 512);
    }
}

// ---------------------------------------------------------------------------
// Leaf: e = emb[words]; 3 gates; K'=384 split; H out as [row][hi128|lo128]
// ---------------------------------------------------------------------------
__global__ __launch_bounds__(256)
void leaf_mfma2(const int* __restrict__ words, const float* __restrict__ emb,
                const ushort_t* __restrict__ Wt2,
                const float* __restrict__ bi, const float* __restrict__ bo,
                const float* __restrict__ bu,
                ushort_t* __restrict__ H2out, float* __restrict__ Cout)
{
    __shared__ ushort_t Bl[2][24 * 512];             // 2 x 24 KB
    const int tid = threadIdx.x, lane = tid & 63, wc = tid >> 6;
    const int l15 = lane & 15, l4 = lane >> 4;
    const int rb = blockIdx.x * 32;

    f32x4 acc[2][2][3];
#pragma unroll
    for (int rt = 0; rt < 2; ++rt)
#pragma unroll
        for (int jbi = 0; jbi < 2; ++jbi)
#pragma unroll
            for (int g = 0; g < 3; ++g) acc[rt][jbi][g] = (f32x4){0.f, 0.f, 0.f, 0.f};

    const int w0 = words[rb + l15];
    const int w1 = words[rb + 16 + l15];
    const float* e0 = emb + (size_t)w0 * 128 + l4 * 8;
    const float* e1 = emb + (size_t)w1 * 128 + l4 * 8;

    short8v AhC[2][4], AlC[2][4];
#pragma unroll
    for (int q = 0; q < 4; ++q) {
        float4 a00 = *(const float4*)(e0 + q * 32);
        float4 a01 = *(const float4*)(e0 + q * 32 + 4);
        float4 a10 = *(const float4*)(e1 + q * 32);
        float4 a11 = *(const float4*)(e1 + q * 32 + 4);
        cvt_hilo(a00, a01, AhC[0][q], AlC[0][q]);
        cvt_hilo(a10, a11, AhC[1][q], AlC[1][q]);
    }

    stage_F(Wt2, &Bl[0][0], 0, wc, lane);
    asm volatile("s_waitcnt vmcnt(0)" ::: "memory");
    __syncthreads();

#pragma unroll
    for (int c = 0; c < 8; ++c) {
        const int cur = c & 1;
        if (c < 7) stage_F(Wt2, &Bl[cur ^ 1][0], c + 1, wc, lane);
#pragma unroll
        for (int jbi = 0; jbi < 2; ++jbi)
#pragma unroll
            for (int g = 0; g < 3; ++g) {
                const int ct = g * 8 + wc + 4 * jbi;
                short8v B = *(const short8v*)(&Bl[cur][ct * 512 + lane * 8]);
                if (c < 4) {
                    acc[0][jbi][g] = __builtin_amdgcn_mfma_f32_16x16x32_bf16(AhC[0][c], B, acc[0][jbi][g], 0, 0, 0);
                    acc[1][jbi][g] = __builtin_amdgcn_mfma_f32_16x16x32_bf16(AhC[1][c], B, acc[1][jbi][g], 0, 0, 0);
                    acc[0][jbi][g] = __builtin_amdgcn_mfma_f32_16x16x32_bf16(AlC[0][c], B, acc[0][jbi][g], 0, 0, 0);
                    acc[1][jbi][g] = __builtin_amdgcn_mfma_f32_16x16x32_bf16(AlC[1][c], B, acc[1][jbi][g], 0, 0, 0);
                } else {
                    acc[0][jbi][g] = __builtin_amdgcn_mfma_f32_16x16x32_bf16(AhC[0][c - 4], B, acc[0][jbi][g], 0, 0, 0);
                    acc[1][jbi][g] = __builtin_amdgcn_mfma_f32_16x16x32_bf16(AhC[1][c - 4], B, acc[1][jbi][g], 0, 0, 0);
                }
            }
        asm volatile("s_waitcnt vmcnt(0)" ::: "memory");
        __syncthreads();
    }

#pragma unroll
    for (int jbi = 0; jbi < 2; ++jbi) {
        const int j = (wc + 4 * jbi) * 16 + l15;
        const float bi_ = bi[j], bo_ = bo[j], bu_ = bu[j];
#pragma unroll
        for (int rt = 0; rt < 2; ++rt)
#pragma unroll
            for (int v = 0; v < 4; ++v) {
                const int row = rb + rt * 16 + l4 * 4 + v;
                float iv = sigf(acc[rt][jbi][0][v] + bi_);
                float ov = sigf(acc[rt][jbi][1][v] + bo_);
                float uv = fmaxf(acc[rt][jbi][2][v] + bu_, 0.f);
                float cc_ = iv * uv;
                float hh  = ov * fmaxf(cc_, 0.f);
                Cout[(size_t)row * 128 + j] = cc_;
                unsigned short hhi = bf16_rne(hh);
                unsigned short hlo = bf16_rne(hh - bf16_f32(hhi));
                H2out[(size_t)row * 256 + j] = hhi;
                H2out[(size_t)row * 256 + 128 + j] = hlo;
            }
    }
}

// ---------------------------------------------------------------------------
// Level (big m): LDS-staged B, A prefetched in regs. BM=32, 4 waves.
// ---------------------------------------------------------------------------
__global__ __launch_bounds__(256)
void level_big(const ushort_t* __restrict__ H2in, const float* __restrict__ Cin,
               const ushort_t* __restrict__ Wt2,
               const float* __restrict__ bUi, const float* __restrict__ bUo,
               const float* __restrict__ bUu, const float* __restrict__ bf1,
               const float* __restrict__ bf2,
               ushort_t* __restrict__ H2out, float* __restrict__ Cout, int n)
{
    __shared__ ushort_t Bl[2][40 * 512];             // 2 x 40 KB
    const int tid = threadIdx.x, lane = tid & 63, wc = tid >> 6;
    const int l15 = lane & 15, l4 = lane >> 4;
    const int rb = blockIdx.x * 32;

    f32x4 acc[2][2][5];
#pragma unroll
    for (int rt = 0; rt < 2; ++rt)
#pragma unroll
        for (int jbi = 0; jbi < 2; ++jbi)
#pragma unroll
            for (int g = 0; g < 5; ++g) acc[rt][jbi][g] = (f32x4){0.f, 0.f, 0.f, 0.f};

    const ushort_t* arow0 = H2in + (size_t)(2 * (rb + l15)) * 256;
    const ushort_t* arow1 = H2in + (size_t)(2 * (rb + 16 + l15)) * 256;

    short8v Ah[2][2], Al[2][2];
    {   // chunk 0: cc=0, csel=0, kf=l4*8
        const int kf = l4 * 8;
        Ah[0][0] = *(const short8v*)(arow0 + kf);
        Ah[0][1] = *(const short8v*)(arow1 + kf);
        Al[0][0] = *(const short8v*)(arow0 + 128 + kf);
        Al[0][1] = *(const short8v*)(arow1 + 128 + kf);
    }
    stage_L(Wt2, &Bl[0][0], 0, wc, lane);
    asm volatile("s_waitcnt vmcnt(0)" ::: "memory");
    __syncthreads();

#pragma unroll
    for (int c = 0; c < 16; ++c) {
        const int cur = c & 1;
        if (c < 15) {
            const int cn = c + 1, ccn = cn & 7;
            const int offn = (ccn >> 2) * 256 + (ccn & 3) * 32 + l4 * 8;
            Ah[cur ^ 1][0] = *(const short8v*)(arow0 + offn);
            Ah[cur ^ 1][1] = *(const short8v*)(arow1 + offn);
            if (cn < 8) {
                Al[cur ^ 1][0] = *(const short8v*)(arow0 + offn + 128);
                Al[cur ^ 1][1] = *(const short8v*)(arow1 + offn + 128);
            }
            stage_L(Wt2, &Bl[cur ^ 1][0], cn, wc, lane);
        }
#pragma unroll
        for (int jbi = 0; jbi < 2; ++jbi)
#pragma unroll
            for (int g = 0; g < 5; ++g) {
                const int ct = g * 8 + wc + 4 * jbi;
                short8v B = *(const short8v*)(&Bl[cur][ct * 512 + lane * 8]);
                acc[0][jbi][g] = __builtin_amdgcn_mfma_f32_16x16x32_bf16(Ah[cur][0], B, acc[0][jbi][g], 0, 0, 0);
                acc[1][jbi][g] = __builtin_amdgcn_mfma_f32_16x16x32_bf16(Ah[cur][1], B, acc[1][jbi][g], 0, 0, 0);
                if (c < 8) {
                    acc[0][jbi][g] = __builtin_amdgcn_mfma_f32_16x16x32_bf16(Al[cur][0], B, acc[0][jbi][g], 0, 0, 0);
                    acc[1][jbi][g] = __builtin_amdgcn_mfma_f32_16x16x32_bf16(Al[cur][1], B, acc[1][jbi][g], 0, 0, 0);
                }
            }
        asm volatile("s_waitcnt vmcnt(0)" ::: "memory");
        __syncthreads();
    }

#pragma unroll
    for (int jbi = 0; jbi < 2; ++jbi) {
        const int j = (wc + 4 * jbi) * 16 + l15;
        const float bi_ = bUi[j], bo_ = bUo[j], bu_ = bUu[j], b1_ = bf1[j], b2_ = bf2[j];
#pragma unroll
        for (int rt = 0; rt < 2; ++rt)
#pragma unroll
            for (int v = 0; v < 4; ++v) {
                const int row = rb + rt * 16 + l4 * 4 + v;
                float iv  = sigf(acc[rt][jbi][0][v] + bi_);
                float ov  = sigf(acc[rt][jbi][1][v] + bo_);
                float uv  = fmaxf(acc[rt][jbi][2][v] + bu_, 0.f);
                float f1v = sigf(acc[rt][jbi][3][v] + b1_);
                float f2v = sigf(acc[rt][jbi][4][v] + b2_);
                float lC = Cin[(size_t)(2 * row) * 128 + j];
                float rC = Cin[(size_t)(2 * row + 1) * 128 + j];
                float cc_ = fmaf(iv, uv, fmaf(f1v, lC, f2v * rC));
                float hh  = ov * fmaxf(cc_, 0.f);
                Cout[(size_t)row * 128 + j] = cc_;
                unsigned short hhi = bf16_rne(hh);
                unsigned short hlo = bf16_rne(hh - bf16_f32(hhi));
                H2out[(size_t)row * 256 + j] = hhi;
                H2out[(size_t)row * 256 + 128 + j] = hlo;
            }
    }
}

// ---------------------------------------------------------------------------
// Level (small m): barrier-free, direct coalesced B loads (L2-hot table)
// ---------------------------------------------------------------------------
__global__ __launch_bounds__(256)
void level_small(const ushort_t* __restrict__ H2in, const float* __restrict__ Cin,
                 const ushort_t* __restrict__ Wt2,
                 const float* __restrict__ bUi, const float* __restrict__ bUo,
                 const float* __restrict__ bUu, const float* __restrict__ bf1,
                 const float* __restrict__ bf2,
                 ushort_t* __restrict__ H2out, float* __restrict__ Cout, int n)
{
    const int tid = threadIdx.x, lane = tid & 63, wc = tid >> 6;
    const int l15 = lane & 15, l4 = lane >> 4;
    const int rb = blockIdx.x * 32;

    int r0 = rb + l15;       if (r0 > n - 1) r0 = n - 1;
    int r1 = rb + 16 + l15;  if (r1 > n - 1) r1 = n - 1;
    const ushort_t* arow0 = H2in + (size_t)(2 * r0) * 256;
    const ushort_t* arow1 = H2in + (size_t)(2 * r1) * 256;

    f32x4 acc[2][2][5];
#pragma unroll
    for (int rt = 0; rt < 2; ++rt)
#pragma unroll
        for (int jbi = 0; jbi < 2; ++jbi)
#pragma unroll
            for (int g = 0; g < 5; ++g) acc[rt][jbi][g] = (f32x4){0.f, 0.f, 0.f, 0.f};

#pragma unroll
    for (int c = 0; c < 16; ++c) {
        const int cc = c & 7;
        const int off = (cc >> 2) * 256 + (cc & 3) * 32 + l4 * 8;
        short8v A0 = *(const short8v*)(arow0 + off);
        short8v A1 = *(const short8v*)(arow1 + off);
        short8v A0l, A1l;
        if (c < 8) {
            A0l = *(const short8v*)(arow0 + off + 128);
            A1l = *(const short8v*)(arow1 + off + 128);
        }
#pragma unroll
        for (int jbi = 0; jbi < 2; ++jbi)
#pragma unroll
            for (int g = 0; g < 5; ++g) {
                const int ct = g * 8 + wc + 4 * jbi;
                short8v B = *(const short8v*)(Wt2 + ((size_t)(c * 40 + ct) * 64 + lane) * 8);
                acc[0][jbi][g] = __builtin_amdgcn_mfma_f32_16x16x32_bf16(A0, B, acc[0][jbi][g], 0, 0, 0);
                acc[1][jbi][g] = __builtin_amdgcn_mfma_f32_16x16x32_bf16(A1, B, acc[1][jbi][g], 0, 0, 0);
                if (c < 8) {
                    acc[0][jbi][g] = __builtin_amdgcn_mfma_f32_16x16x32_bf16(A0l, B, acc[0][jbi][g], 0, 0, 0);
                    acc[1][jbi][g] = __builtin_amdgcn_mfma_f32_16x16x32_bf16(A1l, B, acc[1][jbi][g], 0, 0, 0);
                }
            }
    }

#pragma unroll
    for (int jbi = 0; jbi < 2; ++jbi) {
        const int j = (wc + 4 * jbi) * 16 + l15;
        const float bi_ = bUi[j], bo_ = bUo[j], bu_ = bUu[j], b1_ = bf1[j], b2_ = bf2[j];
#pragma unroll
        for (int rt = 0; rt < 2; ++rt)
#pragma unroll
            for (int v = 0; v < 4; ++v) {
                const int row = rb + rt * 16 + l4 * 4 + v;
                if (row < n) {
                    float iv  = sigf(acc[rt][jbi][0][v] + bi_);
                    float ov  = sigf(acc[rt][jbi][1][v] + bo_);
                    float uv  = fmaxf(acc[rt][jbi][2][v] + bu_, 0.f);
                    float f1v = sigf(acc[rt][jbi][3][v] + b1_);
                    float f2v = sigf(acc[rt][jbi][4][v] + b2_);
                    float lC = Cin[(size_t)(2 * row) * 128 + j];
                    float rC = Cin[(size_t)(2 * row + 1) * 128 + j];
                    float cc_ = fmaf(iv, uv, fmaf(f1v, lC, f2v * rC));
                    float hh  = ov * fmaxf(cc_, 0.f);
                    Cout[(size_t)row * 128 + j] = cc_;
                    unsigned short hhi = bf16_rne(hh);
                    unsigned short hlo = bf16_rne(hh - bf16_f32(hhi));
                    H2out[(size_t)row * 256 + j] = hhi;
                    H2out[(size_t)row * 256 + 128 + j] = hlo;
                }
            }
    }
}

// ---------------------------------------------------------------------------
// Projection: out[r] = (hi+lo)[r] @ P + bP   (one wave per row)
// ---------------------------------------------------------------------------
__global__ __launch_bounds__(256)
void proj2(const ushort_t* __restrict__ H2, const float* __restrict__ P,
           const float* __restrict__ bP, float* __restrict__ out, int total)
{
    int wid  = blockIdx.x * 4 + (threadIdx.x >> 6);
    int lane = threadIdx.x & 63;
    if (wid >= total) return;
    const unsigned* hr = (const unsigned*)(H2 + (size_t)wid * 256);
    unsigned uh = hr[lane];
    unsigned ul = hr[64 + lane];
    float h0 = bf16_f32((unsigned short)(uh & 0xffffu)) + bf16_f32((unsigned short)(ul & 0xffffu));
    float h1 = bf16_f32((unsigned short)(uh >> 16)) + bf16_f32((unsigned short)(ul >> 16));
    const int k0 = 2 * lane, k1 = 2 * lane + 1;
    float a[NCLS];
#pragma unroll
    for (int c2 = 0; c2 < NCLS; ++c2)
        a[c2] = fmaf(h0, P[k0 * NCLS + c2], h1 * P[k1 * NCLS + c2]);
    for (int off = 32; off; off >>= 1)
#pragma unroll
        for (int c2 = 0; c2 < NCLS; ++c2) a[c2] += __shfl_down(a[c2], off, 64);
    if (lane == 0)
#pragma unroll
        for (int c2 = 0; c2 < NCLS; ++c2) out[(size_t)wid * NCLS + c2] = a[c2] + bP[c2];
}

// ---------------------------------------------------------------------------
// Host launcher
// ws: Wt2L@0 (640K) | Wt2F@655360 (192K) | H2@1MiB (67.1M) | CA (33.6M) | CB (16.8M)
// ---------------------------------------------------------------------------
extern "C" void kernel_launch(void* const* d_in, const int* in_sizes, int n_in,
                              void* d_out, int out_size, void* d_ws, size_t ws_size,
                              hipStream_t stream)
{
    const int*   words = (const int*)  d_in[0];
    const float* emb   = (const float*)d_in[1];
    const float* Wi  = (const float*)d_in[2];  const float* bi  = (const float*)d_in[3];
    const float* Wo  = (const float*)d_in[4];  const float* bo  = (const float*)d_in[5];
    const float* Wu  = (const float*)d_in[6];  const float* bu  = (const float*)d_in[7];
    const float* Ui  = (const float*)d_in[8];  const float* bUi = (const float*)d_in[9];
    const float* Uo  = (const float*)d_in[10]; const float* bUo = (const float*)d_in[11];
    const float* Uu  = (const float*)d_in[12]; const float* bUu = (const float*)d_in[13];
    const float* Uf1 = (const float*)d_in[14]; const float* bf1 = (const float*)d_in[15];
    const float* Uf2 = (const float*)d_in[16]; const float* bf2 = (const float*)d_in[17];
    const float* P   = (const float*)d_in[18]; const float* bP  = (const float*)d_in[19];
    float* out = (float*)d_out;

    ushort_t* Wt2L = (ushort_t*)d_ws;
    ushort_t* Wt2F = (ushort_t*)((char*)d_ws + 655360);
    ushort_t* H2   = (ushort_t*)((char*)d_ws + 1048576);
    float*    CA   = (float*)((char*)d_ws + 68157440);
    float*    CB   = (float*)((char*)d_ws + 101711872);

    prep_level_w2<<<1280, 256, 0, stream>>>(Ui, Uo, Uu, Uf1, Uf2, Wt2L);
    prep_leaf_w2<<<384, 256, 0, stream>>>(Wi, Wo, Wu, Wt2F);

    leaf_mfma2<<<NLEAF / 32, 256, 0, stream>>>(words, emb, Wt2F, bi, bo, bu, H2, CA);

    const float* cin = CA;
    float*       cot = CB;
    int n_prev = NLEAF;
    int off_prev = 0;
    int off = NLEAF;
    while (n_prev > 1) {
        int m = n_prev >> 1;
        ushort_t* h_in  = H2 + (size_t)off_prev * 256;
        ushort_t* h_out = H2 + (size_t)off * 256;
        if (m >= 2048) {
            level_big<<<m / 32, 256, 0, stream>>>(
                h_in, cin, Wt2L, bUi, bUo, bUu, bf1, bf2, h_out, cot, m);
        } else {
            level_small<<<(m + 31) / 32, 256, 0, stream>>>(
                h_in, cin, Wt2L, bUi, bUo, bUu, bf1, bf2, h_out, cot, m);
        }
        float* tmp = (float*)cin; cin = cot; cot = tmp;
        off_prev = off;
        off += m;
        n_prev = m;
    }

    int total = off;  // 131071
    proj2<<<(total + 3) / 4, 256, 0, stream>>>(H2, P, bP, out, total);
}

// Round 4
// 374.134 us; speedup vs baseline: 2.8149x; 1.2786x over previous
//
#include <hip/hip_runtime.h>
#include <cstdint>
#include <cstddef>

#define HDIM  128
#define NCLS  5
#define NLEAF 65536

typedef unsigned short ushort_t;
typedef __attribute__((ext_vector_type(8))) short short8v;   // 8 bf16 (4 VGPRs)
typedef __attribute__((ext_vector_type(4))) float f32x4;     // MFMA accumulator

__device__ __forceinline__ float sigf(float x) { return 1.0f / (1.0f + __expf(-x)); }

__device__ __forceinline__ unsigned short bf16_rne(float x) {
    unsigned u = __float_as_uint(x);
    u += 0x7FFFu + ((u >> 16) & 1u);
    return (unsigned short)(u >> 16);
}
__device__ __forceinline__ float bf16_f32(unsigned short h) {
    return __uint_as_float(((unsigned)h) << 16);
}

// ---------------------------------------------------------------------------
// Weight prep into fragment order: Wt2[((chunk*NCT + ct)*64 + lane)*8 + e]
// level: NCT=40, chunks=16 (phys k 512: [0,256)=hi, [256,512)=lo)
// ---------------------------------------------------------------------------
__global__ __launch_bounds__(256)
void prep_level_w2(const float* __restrict__ Ui, const float* __restrict__ Uo,
                   const float* __restrict__ Uu, const float* __restrict__ Uf1,
                   const float* __restrict__ Uf2, ushort_t* __restrict__ Wt2)
{
    int idx = blockIdx.x * 256 + threadIdx.x;        // 16*40*64*8 = 327680
    if (idx >= 327680) return;
    int e    = idx & 7;
    int lane = (idx >> 3) & 63;
    int rest = idx >> 9;
    int ct = rest % 40;
    int chunk = rest / 40;
    int l15 = lane & 15, l4 = lane >> 4;
    int g = ct >> 3, jb = ct & 7;
    int j = jb * 16 + l15;
    int bk = chunk * 32 + l4 * 8 + e;                // [0,512)
    int band = bk >> 8;
    int k = bk & 255;
    float x;
    if      (g == 0) x = Ui[k * 128 + j];
    else if (g == 1) x = Uo[k * 128 + j];
    else if (g == 2) x = Uu[k * 128 + j];
    else if (g == 3) x = (k < 128)  ? Uf1[k * 128 + j] : 0.f;
    else             x = (k >= 128) ? Uf2[(k - 128) * 128 + j] : 0.f;
    unsigned short h = bf16_rne(x);
    if (band) h = bf16_rne(x - bf16_f32(h));
    Wt2[idx] = h;
}

// leaf: NCT=24, chunks=8 (phys k 256: [0,128)=hi, [128,256)=lo)
__global__ __launch_bounds__(256)
void prep_leaf_w2(const float* __restrict__ Wi, const float* __restrict__ Wo,
                  const float* __restrict__ Wu, ushort_t* __restrict__ Wt2)
{
    int idx = blockIdx.x * 256 + threadIdx.x;        // 8*24*64*8 = 98304
    if (idx >= 98304) return;
    int e    = idx & 7;
    int lane = (idx >> 3) & 63;
    int rest = idx >> 9;
    int ct = rest % 24;
    int chunk = rest / 24;
    int l15 = lane & 15, l4 = lane >> 4;
    int g = ct >> 3, jb = ct & 7;
    int j = jb * 16 + l15;
    int bk = chunk * 32 + l4 * 8 + e;                // [0,256)
    int band = bk >> 7;
    int k = bk & 127;
    float x;
    if      (g == 0) x = Wi[k * 128 + j];
    else if (g == 1) x = Wo[k * 128 + j];
    else             x = Wu[k * 128 + j];
    unsigned short h = bf16_rne(x);
    if (band) h = bf16_rne(x - bf16_f32(h));
    Wt2[idx] = h;
}

// ---------------------------------------------------------------------------
// E2 gather: E2[row][hi128|lo128] = hi/lo split of emb[words[row]]
// ---------------------------------------------------------------------------
__global__ __launch_bounds__(256)
void e2_gather(const int* __restrict__ words, const float* __restrict__ emb,
               ushort_t* __restrict__ E2)
{
    int idx = blockIdx.x * 256 + threadIdx.x;        // 65536*128
    int row = idx >> 7, j = idx & 127;
    int w = words[row];
    float x = emb[(size_t)w * 128 + j];
    unsigned short hi = bf16_rne(x);
    unsigned short lo = bf16_rne(x - bf16_f32(hi));
    E2[(size_t)row * 256 + j]       = hi;
    E2[(size_t)row * 256 + 128 + j] = lo;
}

// ---------------------------------------------------------------------------
// Leaf: barrier-free streaming. 512 thr = 8 waves; wave wc owns j-block wc.
// BM=64 (RT=4). K phys chunks: cc in [0,4) hi, cc+4 lo. 36 MFMA / 10 loads per cc.
// NOTE: E2 aliases Cout (CA) -> one barrier before epilogue stores.
// ---------------------------------------------------------------------------
__global__ __launch_bounds__(512)
void leaf_stream(const ushort_t* __restrict__ E2, const ushort_t* __restrict__ Wt2,
                 const float* __restrict__ bi, const float* __restrict__ bo,
                 const float* __restrict__ bu,
                 ushort_t* __restrict__ H2out, float* __restrict__ Cout)
{
    const int tid = threadIdx.x, lane = tid & 63, wc = tid >> 6;
    const int l15 = lane & 15, l4 = lane >> 4;
    const int rb = blockIdx.x * 64;

    f32x4 acc[4][3];
#pragma unroll
    for (int rt = 0; rt < 4; ++rt)
#pragma unroll
        for (int g = 0; g < 3; ++g) acc[rt][g] = (f32x4){0.f, 0.f, 0.f, 0.f};

    const ushort_t* arow[4];
#pragma unroll
    for (int rt = 0; rt < 4; ++rt)
        arow[rt] = E2 + (size_t)(rb + rt * 16 + l15) * 256;

#pragma unroll
    for (int cc = 0; cc < 4; ++cc) {
        const int aoff = cc * 32 + l4 * 8;
        short8v Ah[4], Al[4];
#pragma unroll
        for (int rt = 0; rt < 4; ++rt) {
            Ah[rt] = *(const short8v*)(arow[rt] + aoff);
            Al[rt] = *(const short8v*)(arow[rt] + aoff + 128);
        }
        short8v Bh[3], Bl[3];
#pragma unroll
        for (int g = 0; g < 3; ++g) {
            const int ct = g * 8 + wc;
            Bh[g] = *(const short8v*)(Wt2 + ((size_t)(cc * 24 + ct) * 64 + lane) * 8);
            Bl[g] = *(const short8v*)(Wt2 + ((size_t)((cc + 4) * 24 + ct) * 64 + lane) * 8);
        }
#pragma unroll
        for (int g = 0; g < 3; ++g)
#pragma unroll
            for (int rt = 0; rt < 4; ++rt) {
                acc[rt][g] = __builtin_amdgcn_mfma_f32_16x16x32_bf16(Ah[rt], Bh[g], acc[rt][g], 0, 0, 0);
                acc[rt][g] = __builtin_amdgcn_mfma_f32_16x16x32_bf16(Al[rt], Bh[g], acc[rt][g], 0, 0, 0);
                acc[rt][g] = __builtin_amdgcn_mfma_f32_16x16x32_bf16(Ah[rt], Bl[g], acc[rt][g], 0, 0, 0);
            }
    }

    __syncthreads();   // E2 aliases Cout: all reads complete before any store

    const int j = wc * 16 + l15;
    const float bi_ = bi[j], bo_ = bo[j], bu_ = bu[j];
#pragma unroll
    for (int rt = 0; rt < 4; ++rt)
#pragma unroll
        for (int v = 0; v < 4; ++v) {
            const int row = rb + rt * 16 + l4 * 4 + v;
            float iv = sigf(acc[rt][0][v] + bi_);
            float ov = sigf(acc[rt][1][v] + bo_);
            float uv = fmaxf(acc[rt][2][v] + bu_, 0.f);
            float cc_ = iv * uv;
            float hh  = ov * fmaxf(cc_, 0.f);
            Cout[(size_t)row * 128 + j] = cc_;
            unsigned short hhi = bf16_rne(hh);
            unsigned short hlo = bf16_rne(hh - bf16_f32(hhi));
            H2out[(size_t)row * 256 + j] = hhi;
            H2out[(size_t)row * 256 + 128 + j] = hlo;
        }
}

// ---------------------------------------------------------------------------
// Level streaming kernel. 512 thr = 8 waves; wave wc owns j-block wc.
// BM = 16*RT. Per cc (0..7): csel=cc>>2, koff=(cc&3)*32; 15*RT MFMA, 2*RT+10 loads.
// ---------------------------------------------------------------------------
template<int RT>
__global__ __launch_bounds__(512)
void level_stream(const ushort_t* __restrict__ H2in, const float* __restrict__ Cin,
                  const ushort_t* __restrict__ Wt2,
                  const float* __restrict__ bUi, const float* __restrict__ bUo,
                  const float* __restrict__ bUu, const float* __restrict__ bf1,
                  const float* __restrict__ bf2,
                  ushort_t* __restrict__ H2out, float* __restrict__ Cout, int n)
{
    const int tid = threadIdx.x, lane = tid & 63, wc = tid >> 6;
    const int l15 = lane & 15, l4 = lane >> 4;
    const int rb = blockIdx.x * (16 * RT);

    f32x4 acc[RT][5];
#pragma unroll
    for (int rt = 0; rt < RT; ++rt)
#pragma unroll
        for (int g = 0; g < 5; ++g) acc[rt][g] = (f32x4){0.f, 0.f, 0.f, 0.f};

    const ushort_t* arow[RT];
#pragma unroll
    for (int rt = 0; rt < RT; ++rt)
        arow[rt] = H2in + (size_t)(2 * (rb + rt * 16 + l15)) * 256;

#pragma unroll
    for (int cc = 0; cc < 8; ++cc) {
        const int aoff = (cc >> 2) * 256 + (cc & 3) * 32 + l4 * 8;  // csel*256 + koff
        short8v Ah[RT], Al[RT];
#pragma unroll
        for (int rt = 0; rt < RT; ++rt) {
            Ah[rt] = *(const short8v*)(arow[rt] + aoff);
            Al[rt] = *(const short8v*)(arow[rt] + aoff + 128);
        }
        short8v Bh[5], Bl[5];
#pragma unroll
        for (int g = 0; g < 5; ++g) {
            const int ct = g * 8 + wc;
            Bh[g] = *(const short8v*)(Wt2 + ((size_t)(cc * 40 + ct) * 64 + lane) * 8);
            Bl[g] = *(const short8v*)(Wt2 + ((size_t)((cc + 8) * 40 + ct) * 64 + lane) * 8);
        }
#pragma unroll
        for (int g = 0; g < 5; ++g)
#pragma unroll
            for (int rt = 0; rt < RT; ++rt) {
                acc[rt][g] = __builtin_amdgcn_mfma_f32_16x16x32_bf16(Ah[rt], Bh[g], acc[rt][g], 0, 0, 0);
                acc[rt][g] = __builtin_amdgcn_mfma_f32_16x16x32_bf16(Al[rt], Bh[g], acc[rt][g], 0, 0, 0);
                acc[rt][g] = __builtin_amdgcn_mfma_f32_16x16x32_bf16(Ah[rt], Bl[g], acc[rt][g], 0, 0, 0);
            }
    }

    const int j = wc * 16 + l15;
    const float bi_ = bUi[j], bo_ = bUo[j], bu_ = bUu[j], b1_ = bf1[j], b2_ = bf2[j];
#pragma unroll
    for (int rt = 0; rt < RT; ++rt)
#pragma unroll
        for (int v = 0; v < 4; ++v) {
            const int row = rb + rt * 16 + l4 * 4 + v;
            float iv  = sigf(acc[rt][0][v] + bi_);
            float ov  = sigf(acc[rt][1][v] + bo_);
            float uv  = fmaxf(acc[rt][2][v] + bu_, 0.f);
            float f1v = sigf(acc[rt][3][v] + b1_);
            float f2v = sigf(acc[rt][4][v] + b2_);
            float lC = Cin[(size_t)(2 * row) * 128 + j];
            float rC = Cin[(size_t)(2 * row + 1) * 128 + j];
            float cc_ = fmaf(iv, uv, fmaf(f1v, lC, f2v * rC));
            float hh  = ov * fmaxf(cc_, 0.f);
            Cout[(size_t)row * 128 + j] = cc_;
            unsigned short hhi = bf16_rne(hh);
            unsigned short hlo = bf16_rne(hh - bf16_f32(hhi));
            H2out[(size_t)row * 256 + j] = hhi;
            H2out[(size_t)row * 256 + 128 + j] = hlo;
        }
}

// ---------------------------------------------------------------------------
// Tiny level: 1 wave per block; grid = (ceil(m/16), 8); jb = blockIdx.y.
// BM=16 with row clamping; for the latency-bound tail levels.
// ---------------------------------------------------------------------------
__global__ __launch_bounds__(64)
void level_tiny(const ushort_t* __restrict__ H2in, const float* __restrict__ Cin,
                const ushort_t* __restrict__ Wt2,
                const float* __restrict__ bUi, const float* __restrict__ bUo,
                const float* __restrict__ bUu, const float* __restrict__ bf1,
                const float* __restrict__ bf2,
                ushort_t* __restrict__ H2out, float* __restrict__ Cout, int n)
{
    const int lane = threadIdx.x;
    const int l15 = lane & 15, l4 = lane >> 4;
    const int jb = blockIdx.y;
    const int rb = blockIdx.x * 16;

    int prow = rb + l15; if (prow > n - 1) prow = n - 1;
    const ushort_t* arow = H2in + (size_t)(2 * prow) * 256;

    f32x4 acc[5];
#pragma unroll
    for (int g = 0; g < 5; ++g) acc[g] = (f32x4){0.f, 0.f, 0.f, 0.f};

#pragma unroll
    for (int cc = 0; cc < 8; ++cc) {
        const int aoff = (cc >> 2) * 256 + (cc & 3) * 32 + l4 * 8;
        short8v Ah = *(const short8v*)(arow + aoff);
        short8v Al = *(const short8v*)(arow + aoff + 128);
#pragma unroll
        for (int g = 0; g < 5; ++g) {
            const int ct = g * 8 + jb;
            short8v Bh = *(const short8v*)(Wt2 + ((size_t)(cc * 40 + ct) * 64 + lane) * 8);
            short8v Bl = *(const short8v*)(Wt2 + ((size_t)((cc + 8) * 40 + ct) * 64 + lane) * 8);
            acc[g] = __builtin_amdgcn_mfma_f32_16x16x32_bf16(Ah, Bh, acc[g], 0, 0, 0);
            acc[g] = __builtin_amdgcn_mfma_f32_16x16x32_bf16(Al, Bh, acc[g], 0, 0, 0);
            acc[g] = __builtin_amdgcn_mfma_f32_16x16x32_bf16(Ah, Bl, acc[g], 0, 0, 0);
        }
    }

    const int j = jb * 16 + l15;
    const float bi_ = bUi[j], bo_ = bUo[j], bu_ = bUu[j], b1_ = bf1[j], b2_ = bf2[j];
#pragma unroll
    for (int v = 0; v < 4; ++v) {
        const int row = rb + l4 * 4 + v;
        if (row < n) {
            float iv  = sigf(acc[0][v] + bi_);
            float ov  = sigf(acc[1][v] + bo_);
            float uv  = fmaxf(acc[2][v] + bu_, 0.f);
            float f1v = sigf(acc[3][v] + b1_);
            float f2v = sigf(acc[4][v] + b2_);
            float lC = Cin[(size_t)(2 * row) * 128 + j];
            float rC = Cin[(size_t)(2 * row + 1) * 128 + j];
            float cc_ = fmaf(iv, uv, fmaf(f1v, lC, f2v * rC));
            float hh  = ov * fmaxf(cc_, 0.f);
            Cout[(size_t)row * 128 + j] = cc_;
            unsigned short hhi = bf16_rne(hh);
            unsigned short hlo = bf16_rne(hh - bf16_f32(hhi));
            H2out[(size_t)row * 256 + j] = hhi;
            H2out[(size_t)row * 256 + 128 + j] = hlo;
        }
    }
}

// ---------------------------------------------------------------------------
// Projection: out[r] = (hi+lo)[r] @ P + bP   (one wave per row)
// ---------------------------------------------------------------------------
__global__ __launch_bounds__(256)
void proj2(const ushort_t* __restrict__ H2, const float* __restrict__ P,
           const float* __restrict__ bP, float* __restrict__ out, int total)
{
    int wid  = blockIdx.x * 4 + (threadIdx.x >> 6);
    int lane = threadIdx.x & 63;
    if (wid >= total) return;
    const unsigned* hr = (const unsigned*)(H2 + (size_t)wid * 256);
    unsigned uh = hr[lane];
    unsigned ul = hr[64 + lane];
    float h0 = bf16_f32((unsigned short)(uh & 0xffffu)) + bf16_f32((unsigned short)(ul & 0xffffu));
    float h1 = bf16_f32((unsigned short)(uh >> 16)) + bf16_f32((unsigned short)(ul >> 16));
    const int k0 = 2 * lane, k1 = 2 * lane + 1;
    float a[NCLS];
#pragma unroll
    for (int c2 = 0; c2 < NCLS; ++c2)
        a[c2] = fmaf(h0, P[k0 * NCLS + c2], h1 * P[k1 * NCLS + c2]);
    for (int off = 32; off; off >>= 1)
#pragma unroll
        for (int c2 = 0; c2 < NCLS; ++c2) a[c2] += __shfl_down(a[c2], off, 64);
    if (lane == 0)
#pragma unroll
        for (int c2 = 0; c2 < NCLS; ++c2) out[(size_t)wid * NCLS + c2] = a[c2] + bP[c2];
}

// ---------------------------------------------------------------------------
// Host launcher
// ws: Wt2L@0 (640K) | Wt2F@655360 (192K) | H2@1MiB (67.1M) | CA/E2 (33.55M) | CB (16.78M)
// E2 aliases CA (leaf reads E2 fully before writing CA; in-kernel barrier).
// ---------------------------------------------------------------------------
extern "C" void kernel_launch(void* const* d_in, const int* in_sizes, int n_in,
                              void* d_out, int out_size, void* d_ws, size_t ws_size,
                              hipStream_t stream)
{
    const int*   words = (const int*)  d_in[0];
    const float* emb   = (const float*)d_in[1];
    const float* Wi  = (const float*)d_in[2];  const float* bi  = (const float*)d_in[3];
    const float* Wo  = (const float*)d_in[4];  const float* bo  = (const float*)d_in[5];
    const float* Wu  = (const float*)d_in[6];  const float* bu  = (const float*)d_in[7];
    const float* Ui  = (const float*)d_in[8];  const float* bUi = (const float*)d_in[9];
    const float* Uo  = (const float*)d_in[10]; const float* bUo = (const float*)d_in[11];
    const float* Uu  = (const float*)d_in[12]; const float* bUu = (const float*)d_in[13];
    const float* Uf1 = (const float*)d_in[14]; const float* bf1 = (const float*)d_in[15];
    const float* Uf2 = (const float*)d_in[16]; const float* bf2 = (const float*)d_in[17];
    const float* P   = (const float*)d_in[18]; const float* bP  = (const float*)d_in[19];
    float* out = (float*)d_out;

    ushort_t* Wt2L = (ushort_t*)d_ws;
    ushort_t* Wt2F = (ushort_t*)((char*)d_ws + 655360);
    ushort_t* H2   = (ushort_t*)((char*)d_ws + 1048576);
    float*    CA   = (float*)((char*)d_ws + 68157440);
    float*    CB   = (float*)((char*)d_ws + 101711872);
    ushort_t* E2   = (ushort_t*)CA;              // aliases CA (see leaf_stream)

    prep_level_w2<<<1280, 256, 0, stream>>>(Ui, Uo, Uu, Uf1, Uf2, Wt2L);
    prep_leaf_w2<<<384, 256, 0, stream>>>(Wi, Wo, Wu, Wt2F);
    e2_gather<<<32768, 256, 0, stream>>>(words, emb, E2);

    leaf_stream<<<NLEAF / 64, 512, 0, stream>>>(E2, Wt2F, bi, bo, bu, H2, CA);

    const float* cin = CA;
    float*       cot = CB;
    int n_prev = NLEAF;
    int off_prev = 0;
    int off = NLEAF;
    while (n_prev > 1) {
        int m = n_prev >> 1;
        ushort_t* h_in  = H2 + (size_t)off_prev * 256;
        ushort_t* h_out = H2 + (size_t)off * 256;
        if (m >= 16384) {
            level_stream<4><<<m / 64, 512, 0, stream>>>(
                h_in, cin, Wt2L, bUi, bUo, bUu, bf1, bf2, h_out, cot, m);
        } else if (m >= 8192) {
            level_stream<2><<<m / 32, 512, 0, stream>>>(
                h_in, cin, Wt2L, bUi, bUo, bUu, bf1, bf2, h_out, cot, m);
        } else {
            level_tiny<<<dim3((m + 15) / 16, 8), 64, 0, stream>>>(
                h_in, cin, Wt2L, bUi, bUo, bUu, bf1, bf2, h_out, cot, m);
        }
        float* tmp = (float*)cin; cin = cot; cot = tmp;
        off_prev = off;
        off += m;
        n_prev = m;
    }

    int total = off;  // 131071
    proj2<<<(total + 3) / 4, 256, 0, stream>>>(H2, P, bP, out, total);
}